// Round 11
// baseline (196.445 us; speedup 1.0000x reference)
//
#include <hip/hip_runtime.h>
#include <hip/hip_bf16.h>

#define B_   512
#define C_   256
#define N_   81                 // tokens per batch (9x9)
#define M_   (B_ * N_)          // 41472
#define KNN  9

// fused-kernel LDS layout (bytes)
#define A_OFF   0               // A: 81 rows x 512B bf16, T2-swizzled
#define Q_OFF   41472           // q (later v), same layout
#define K_OFF   82944           // k (later obuf), same layout
#define WT_OFF  124416          // W tiles: 2 x 16384 (32 j-rows x 512B)
#define WG_OFF  157184          // wgt bf16 [81][4][9]; later psl f32 [2][2][256]
#define SMEM_SZ 163016

typedef __attribute__((ext_vector_type(8))) short short8;
typedef __attribute__((ext_vector_type(4))) float f32x4;
typedef __attribute__((ext_vector_type(4))) ushort u16x4;
typedef __attribute__((ext_vector_type(8))) ushort u16x8;

#define GLD16(g, l) __builtin_amdgcn_global_load_lds(                      \
    (const __attribute__((address_space(1))) void*)(g),                    \
    (__attribute__((address_space(3))) void*)(l), 16, 0, 0)

__device__ __forceinline__ float bf2f(ushort u) {
  union { uint i; float f; } c; c.i = (uint)u << 16; return c.f;
}
__device__ __forceinline__ ushort f2bf(float f) {
  __hip_bfloat16 h = __float2bfloat16(f); return *(ushort*)&h;
}

// ---------------------------------------------------------------- kernel A1
// Transpose/split, grid 4096 = (batch, 32-ch chunk). Writes the pre-swizzled
// 12288-B hl image per (b,ch) into hlbuf (rows 81..95 zeroed) + tokb hi rows.
__global__ __launch_bounds__(256) void split_kernel(
    const float* __restrict__ x, ushort* __restrict__ tokb,
    char* __restrict__ hlbuf) {
  __shared__ __align__(16) float raw[32 * 81];   // 10368 B
  const int bid = blockIdx.x;
  const int b = bid >> 3, ch = bid & 7;
  const int tid = threadIdx.x;
  const float* src = x + (size_t)b * (C_ * N_) + ch * 32 * N_;
#pragma unroll
  for (int it = 0; it < 3; ++it) {
    int e4 = tid + it * 256;
    if (e4 < 648) *(f32x4*)&raw[e4 * 4] = *(const f32x4*)&src[e4 * 4];
  }
  char* dst = hlbuf + (size_t)bid * 12288;
  for (int p = tid; p < 480; p += 256)
    *(uint*)(dst + (81 + p / 32) * 128 + (p & 31) * 4) = 0u;
  __syncthreads();
#pragma unroll
  for (int it = 0; it < 6; ++it) {
    int p = tid + it * 256;
    if (p < 1296) {
      int n = p >> 4, q = p & 15;
      float v0 = raw[(2 * q) * N_ + n];
      float v1 = raw[(2 * q + 1) * N_ + n];
      __hip_bfloat16 h0 = __float2bfloat16(v0);
      __hip_bfloat16 h1 = __float2bfloat16(v1);
      float r0 = v0 - __bfloat162float(h0);
      float r1 = v1 - __bfloat162float(h1);
      __hip_bfloat16 g0 = __float2bfloat16(r0);
      __hip_bfloat16 g1 = __float2bfloat16(r1);
      uint hp = (uint)(*(ushort*)&h0) | ((uint)(*(ushort*)&h1) << 16);
      uint lp = (uint)(*(ushort*)&g0) | ((uint)(*(ushort*)&g1) << 16);
      int off = (((q >> 2) << 4) ^ (((n >> 1) & 3) << 4)) + ((q & 3) << 2);
      int hs = (n & 1) << 6;
      *(uint*)(dst + n * 128 + hs + off) = hp;
      *(uint*)(dst + n * 128 + (hs ^ 64) + off) = lp;
      *(uint*)&tokb[((size_t)(b * N_ + n)) * 256 + ch * 32 + 2 * q] = hp;
    }
  }
}

// ---------------------------------------------------------------- kernel A2
// Per batch: 4-term MFMA gram from pre-swizzled hl chunks, diag from G,
// 9-smallest selection. (verified r7-r9)
__global__ __launch_bounds__(256) void knn_kernel(
    const char* __restrict__ hlbuf, int* __restrict__ knn_idx) {
  __shared__ __align__(16) char smem[31488];
  __shared__ float sqv[96];
  const int b = blockIdx.x;
  const int tid = threadIdx.x;
  const int w = tid >> 6, lane = tid & 63;
  const int wr = w >> 1, wc = w & 1;
  const int l15 = lane & 15;
  const int g16 = lane >> 4;

  const char* srcb = hlbuf + (size_t)b * 8 * 12288;
#pragma unroll
  for (int it = 0; it < 3; ++it) {
    int idx = it * 256 + tid;
    GLD16(srcb + idx * 16, smem + idx * 16);
  }
  f32x4 acc[3][3];
#pragma unroll
  for (int i = 0; i < 3; ++i)
#pragma unroll
    for (int j = 0; j < 3; ++j) acc[i][j] = {0.f, 0.f, 0.f, 0.f};

#pragma unroll
  for (int ch = 0; ch < 8; ++ch) {
    char* cur = smem + (ch & 1) * 12288;
    char* nxt = smem + ((ch + 1) & 1) * 12288;
    if (ch < 7) {
      const char* s2 = srcb + (size_t)(ch + 1) * 12288;
#pragma unroll
      for (int it = 0; it < 3; ++it) {
        int idx = it * 256 + tid;
        GLD16(s2 + idx * 16, nxt + idx * 16);
      }
      asm volatile("s_waitcnt vmcnt(3)" ::: "memory");
    } else {
      asm volatile("s_waitcnt vmcnt(0)" ::: "memory");
    }
    __builtin_amdgcn_s_barrier();
    __builtin_amdgcn_sched_barrier(0);
    short8 ah[3], al[3], bh[3], bl[3];
#pragma unroll
    for (int i = 0; i < 3; ++i) {
      int ra = wr * 48 + i * 16 + l15;
      int basea = ra * 128 + ((g16 << 4) ^ (((ra >> 1) & 3) << 4));
      int hsa = (ra & 1) << 6;
      ah[i] = *(const short8*)(cur + basea + hsa);
      al[i] = *(const short8*)(cur + basea + (hsa ^ 64));
      int rb = wc * 48 + i * 16 + l15;
      int baseb = rb * 128 + ((g16 << 4) ^ (((rb >> 1) & 3) << 4));
      int hsb = (rb & 1) << 6;
      bh[i] = *(const short8*)(cur + baseb + hsb);
      bl[i] = *(const short8*)(cur + baseb + (hsb ^ 64));
    }
#pragma unroll
    for (int i = 0; i < 3; ++i)
#pragma unroll
      for (int j = 0; j < 3; ++j) {
        acc[i][j] = __builtin_amdgcn_mfma_f32_16x16x32_bf16(
            ah[i], bh[j], acc[i][j], 0, 0, 0);
        acc[i][j] = __builtin_amdgcn_mfma_f32_16x16x32_bf16(
            ah[i], bl[j], acc[i][j], 0, 0, 0);
        acc[i][j] = __builtin_amdgcn_mfma_f32_16x16x32_bf16(
            al[i], bh[j], acc[i][j], 0, 0, 0);
        acc[i][j] = __builtin_amdgcn_mfma_f32_16x16x32_bf16(
            al[i], bl[j], acc[i][j], 0, 0, 0);
      }
    __builtin_amdgcn_sched_barrier(0);
    __builtin_amdgcn_s_barrier();
  }
  float* G = (float*)smem;
#pragma unroll
  for (int i = 0; i < 3; ++i) {
    const int row0 = wr * 48 + i * 16 + ((lane >> 4) << 2);
#pragma unroll
    for (int j = 0; j < 3; ++j) {
      const int col = wc * 48 + j * 16 + l15;
#pragma unroll
      for (int reg = 0; reg < 4; ++reg) {
        const int row = row0 + reg;
        if (row < N_) G[row * 97 + col] = acc[i][j][reg];
      }
    }
  }
  __syncthreads();
  if (tid < N_) sqv[tid] = G[tid * 97 + tid];
  __syncthreads();
  if (tid < N_) {
    const int n = tid;
    const float sn = sqv[n];
    const float* grow = &G[n * 97];
    float bd[KNN]; int bi[KNN];
#pragma unroll
    for (int k = 0; k < KNN; ++k) { bd[k] = 3.4e38f; bi[k] = 0; }
    for (int m = 0; m < N_; ++m) {
      float d2 = sn + sqv[m] - 2.f * grow[m];
      float wv = bd[0]; int wi = 0;
#pragma unroll
      for (int k = 1; k < KNN; ++k) {
        bool g_ = bd[k] > wv;
        wv = g_ ? bd[k] : wv;
        wi = g_ ? k : wi;
      }
      bool repl = d2 < wv;
#pragma unroll
      for (int k = 0; k < KNN; ++k) {
        bool here = repl & (wi == k);
        bd[k] = here ? d2 : bd[k];
        bi[k] = here ? m : bi[k];
      }
    }
#pragma unroll
    for (int k = 0; k < KNN; ++k)
      knn_idx[((size_t)b * N_ + n) * KNN + k] = bi[k];
  }
}

// ---------------------------------------------------------------- kernel W
__global__ __launch_bounds__(256) void pack_w_kernel(
    const float* __restrict__ wq, const float* __restrict__ bq,
    const float* __restrict__ wk, const float* __restrict__ bk,
    const float* __restrict__ wv, const float* __restrict__ bv,
    ushort* __restrict__ wcat, float* __restrict__ bcat) {
  const int j = blockIdx.x, c = threadIdx.x;
  const int sel = j >> 8, jr = j & 255;
  const float* W  = sel == 0 ? wq : (sel == 1 ? wk : wv);
  const float* Bb = sel == 0 ? bq : (sel == 1 ? bk : bv);
  wcat[(size_t)j * 256 + c] = f2bf(W[jr * 256 + c]);
  if (c == 0) bcat[j] = Bb[jr];
}

// ---------------------------------------------------------------- kernel F
// Fused per-batch: q,k GEMM (LDS) -> attention weights -> v = A@Wv^T + bv
// (LDS, overlays q) -> out[m][c] = sum_k w[h(c),k] * v[nb_k][c] (head = c>>6,
// the OUTPUT column's head -- r10's PA factorization mixed heads and failed)
// -> coalesced store + per-batch BN partial sums.
// 768 threads (12 waves), 163 KB LDS, 1 block/CU.
#define STAGE_W(JB, BUF) do {                                              \
    int jr_ = lane >> 5, kp_ = (lane & 31) * 16;                           \
    _Pragma("unroll")                                                      \
    for (int rr_ = 0; rr_ < 2; ++rr_) {                                    \
      int i_ = w + rr_ * 8;                                                \
      int jrow_ = 2 * i_ + jr_;                                            \
      int kl_ = kp_ ^ ((jrow_ & 7) << 4);                                  \
      GLD16((const char*)wcat + (size_t)((JB) + jrow_) * 512 + kl_,        \
            smem + WT_OFF + (BUF) * 16384 + i_ * 1024 + lane * 16);        \
    }                                                                      \
  } while (0)

__global__ __launch_bounds__(768) void fused_kernel(
    const ushort* __restrict__ tokb, const ushort* __restrict__ wcat,
    const float* __restrict__ bcat, const int* __restrict__ kidx,
    const float* __restrict__ a, ushort* __restrict__ outNC,
    float* __restrict__ ps, float* __restrict__ ps2) {
  __shared__ __align__(16) char smem[SMEM_SZ];
  const int bid = blockIdx.x;
  const int b = (bid & 7) * 64 + (bid >> 3);   // XCD-bijective batch swizzle
  const int tid = threadIdx.x;
  const int w = tid >> 6, lane = tid & 63;
  const int rf = w >> 1, jf = w & 1;
  const int l15 = lane & 15;
  const int kg = (lane >> 4) << 4;             // 16B k-group offset

  int ra = rf * 16 + l15; ra = ra > 80 ? 80 : ra;   // A row (clamped pad)
  const int aswz = (ra & 7) << 4;
  const int jrow = jf * 16 + l15;                   // W-tile local j row
  const int wswz = (jrow & 7) << 4;
  const int r0 = rf * 16 + ((lane >> 4) << 2);      // C row base

  // ---- stage A (81 x 512B) : chunks i = w + 12r, rows {2i, 2i+1}
  {
    const char* tb = (const char*)tokb + (size_t)b * N_ * 512;
    int ric = lane >> 5, kp = (lane & 31) * 16;
#pragma unroll
    for (int rr = 0; rr < 4; ++rr) {
      int i = w + rr * 12;
      if (i <= 40) {   // i=40 lanes>=32 overrun 512B into qbuf row0: benign
        int row = 2 * i + ric;
        int kl = kp ^ ((row & 7) << 4);
        GLD16(tb + (size_t)row * 512 + kl, smem + i * 1024 + lane * 16);
      }
    }
  }
  if (w < 8) STAGE_W(0, 0);
  asm volatile("s_waitcnt vmcnt(0)" ::: "memory");
  __builtin_amdgcn_s_barrier();
  __builtin_amdgcn_sched_barrier(0);

  // ================= sweep 1: q,k (j 0..511, 16 tiles of 32) =============
  for (int jt = 0; jt < 16; ++jt) {
    const int cur = jt & 1;
    if (jt < 15) {
      if (w < 8) STAGE_W(32 * (jt + 1), cur ^ 1);
      asm volatile("s_waitcnt vmcnt(2)" ::: "memory");
    } else {
      asm volatile("s_waitcnt vmcnt(0)" ::: "memory");
    }
    __builtin_amdgcn_s_barrier();
    __builtin_amdgcn_sched_barrier(0);
    const char* Wb = smem + WT_OFF + cur * 16384;
    f32x4 acc = {0.f, 0.f, 0.f, 0.f};
#pragma unroll
    for (int kk = 0; kk < 8; ++kk) {
      short8 af = *(const short8*)(smem + ra * 512 + ((kk * 64 + kg) ^ aswz));
      short8 wf = *(const short8*)(Wb + jrow * 512 + ((kk * 64 + kg) ^ wswz));
      acc = __builtin_amdgcn_mfma_f32_16x16x32_bf16(af, wf, acc, 0, 0, 0);
    }
    const float bias = bcat[jt * 32 + jf * 16 + l15];
    char* dst = smem + (jt < 8 ? Q_OFF : K_OFF);
    const int colb = ((jt & 7) * 32 + jf * 16 + l15) * 2;
#pragma unroll
    for (int reg = 0; reg < 4; ++reg) {
      int r = r0 + reg;
      if (r < 81)
        *(ushort*)(dst + r * 512 + (colb ^ ((r & 7) << 4))) =
            f2bf(acc[reg] + bias);
    }
    asm volatile("s_waitcnt lgkmcnt(0)" ::: "memory");
    __builtin_amdgcn_sched_barrier(0);
    __builtin_amdgcn_s_barrier();
  }

  // ================= attention: scores + softmax -> wgt bf16 =============
  const int* nbbase = kidx + (size_t)b * N_ * KNN;
  {
    const f32x4 a4 = *(const f32x4*)(a + lane * 4);
    for (int rnd = 0; rnd < 7; ++rnd) {
      int m = w + rnd * 12;
      if (m < 81) {
        u16x4 qu = *(const u16x4*)(smem + Q_OFF + m * 512 +
                                   ((lane * 8) ^ ((m & 7) << 4)));
        float q0 = bf2f(qu[0]), q1 = bf2f(qu[1]);
        float q2 = bf2f(qu[2]), q3 = bf2f(qu[3]);
        float sc[KNN];
#pragma unroll
        for (int k = 0; k < KNN; ++k) {
          int nbk = __builtin_amdgcn_readfirstlane(nbbase[m * KNN + k]);
          u16x4 ku = *(const u16x4*)(smem + K_OFF + nbk * 512 +
                                     ((lane * 8) ^ ((nbk & 7) << 4)));
          float t0 = q0 + bf2f(ku[0]); t0 = fmaxf(t0, 0.2f * t0);
          float t1 = q1 + bf2f(ku[1]); t1 = fmaxf(t1, 0.2f * t1);
          float t2 = q2 + bf2f(ku[2]); t2 = fmaxf(t2, 0.2f * t2);
          float t3 = q3 + bf2f(ku[3]); t3 = fmaxf(t3, 0.2f * t3);
          float p = t0 * a4[0] + t1 * a4[1] + t2 * a4[2] + t3 * a4[3];
          p += __shfl_xor(p, 1, 16);
          p += __shfl_xor(p, 2, 16);
          p += __shfl_xor(p, 4, 16);
          p += __shfl_xor(p, 8, 16);
          sc[k] = p;
        }
        float mx = sc[0];
#pragma unroll
        for (int k = 1; k < KNN; ++k) mx = fmaxf(mx, sc[k]);
        float s = 0.f;
#pragma unroll
        for (int k = 0; k < KNN; ++k) {
          sc[k] = __builtin_amdgcn_exp2f((sc[k] - mx) * 1.44269504f);
          s += sc[k];
        }
        const float inv = __builtin_amdgcn_rcpf(s);
        float mwv = sc[0];
#pragma unroll
        for (int k = 1; k < KNN; ++k) mwv = (l15 == k) ? sc[k] : mwv;
        if (l15 < KNN)
          *(ushort*)(smem + WG_OFF +
                     (((m << 2) + (lane >> 4)) * KNN + l15) * 2) =
              f2bf(mwv * inv);
      }
    }
  }
  if (w < 8) STAGE_W(512, 0);            // prefetch v-tile0
  asm volatile("s_waitcnt lgkmcnt(0)" ::: "memory");
  __builtin_amdgcn_sched_barrier(0);
  __builtin_amdgcn_s_barrier();

  // ================= sweep 2: v = A@Wv^T + bv -> LDS (overlays q) ========
  for (int jt = 0; jt < 8; ++jt) {
    const int cur = jt & 1;
    if (jt < 7) {
      if (w < 8) STAGE_W(512 + 32 * (jt + 1), cur ^ 1);
      asm volatile("s_waitcnt vmcnt(2)" ::: "memory");
    } else {
      asm volatile("s_waitcnt vmcnt(0)" ::: "memory");
    }
    __builtin_amdgcn_s_barrier();
    __builtin_amdgcn_sched_barrier(0);
    const char* Wb = smem + WT_OFF + cur * 16384;
    f32x4 acc = {0.f, 0.f, 0.f, 0.f};
#pragma unroll
    for (int kk = 0; kk < 8; ++kk) {
      short8 af = *(const short8*)(smem + A_OFF + ra * 512 +
                                   ((kk * 64 + kg) ^ aswz));
      short8 wf = *(const short8*)(Wb + jrow * 512 + ((kk * 64 + kg) ^ wswz));
      acc = __builtin_amdgcn_mfma_f32_16x16x32_bf16(af, wf, acc, 0, 0, 0);
    }
    const int col = jt * 32 + jf * 16 + l15;
    const float bias = bcat[512 + col];
#pragma unroll
    for (int reg = 0; reg < 4; ++reg) {
      int r = r0 + reg;
      if (r < 81)
        *(ushort*)(smem + Q_OFF + r * 512 + ((col * 2) ^ ((r & 7) << 4))) =
            f2bf(acc[reg] + bias);
    }
    asm volatile("s_waitcnt lgkmcnt(0)" ::: "memory");
    __builtin_amdgcn_sched_barrier(0);
    __builtin_amdgcn_s_barrier();
  }

  // ========== out[m][c] = sum_k w[h(c),k]*v[nb_k][c]  (obuf -> K) ========
  if (tid < 648) {
    const int m = tid >> 3, cg0 = tid & 7;
    const int mswz = (m & 7) << 4;
    int nb[KNN];
#pragma unroll
    for (int k = 0; k < KNN; ++k) nb[k] = nbbase[m * KNN + k];
#pragma unroll
    for (int h = 0; h < 4; ++h) {
      float wv[KNN];
#pragma unroll
      for (int k = 0; k < KNN; ++k)
        wv[k] = bf2f(*(const ushort*)(smem + WG_OFF +
                                      (((m << 2) + h) * KNN + k) * 2));
#pragma unroll
      for (int rr = 0; rr < 2; ++rr) {
        int cg = h * 16 + rr * 8 + cg0;        // col group of 4 channels
        f32x4 o4 = {0.f, 0.f, 0.f, 0.f};
#pragma unroll
        for (int k = 0; k < KNN; ++k) {
          u16x4 vv = *(const u16x4*)(smem + Q_OFF + nb[k] * 512 +
                                     ((cg * 8) ^ ((nb[k] & 7) << 4)));
          o4[0] = __builtin_fmaf(wv[k], bf2f(vv[0]), o4[0]);
          o4[1] = __builtin_fmaf(wv[k], bf2f(vv[1]), o4[1]);
          o4[2] = __builtin_fmaf(wv[k], bf2f(vv[2]), o4[2]);
          o4[3] = __builtin_fmaf(wv[k], bf2f(vv[3]), o4[3]);
        }
        u16x4 o;
        o[0] = f2bf(o4[0]); o[1] = f2bf(o4[1]);
        o[2] = f2bf(o4[2]); o[3] = f2bf(o4[3]);
        *(u16x4*)(smem + K_OFF + m * 512 + ((cg * 8) ^ mswz)) = o;
      }
    }
  }
  asm volatile("s_waitcnt lgkmcnt(0)" ::: "memory");
  __builtin_amdgcn_sched_barrier(0);
  __builtin_amdgcn_s_barrier();

  // ===== coalesced unswizzling copy obuf -> outNC  +  BN partials ========
  {
    ushort* dstg = outNC + (size_t)b * N_ * 256;
    for (int off = tid * 16; off < N_ * 512; off += 768 * 16) {
      int r = off >> 9, co = off & 511;
      u16x8 vv = *(const u16x8*)(smem + K_OFF + r * 512 +
                                 (co ^ ((r & 7) << 4)));
      *(u16x8*)((char*)dstg + (size_t)r * 512 + co) = vv;
    }
  }
  if (tid < 512) {
    const int half = tid >> 8, c = tid & 255;
    const int rbeg = half * 41, rend = half ? 81 : 41;
    float s = 0.f, s2 = 0.f;
    for (int rr = rbeg; rr < rend; ++rr) {
      float v = bf2f(*(const ushort*)(smem + K_OFF + rr * 512 +
                                      ((c * 2) ^ ((rr & 7) << 4))));
      s += v; s2 = __builtin_fmaf(v, v, s2);
    }
    *(float*)(smem + WG_OFF + (half * 256 + c) * 4) = s;
    *(float*)(smem + WG_OFF + 2048 + (half * 256 + c) * 4) = s2;
  }
  asm volatile("s_waitcnt lgkmcnt(0)" ::: "memory");
  __builtin_amdgcn_sched_barrier(0);
  __builtin_amdgcn_s_barrier();
  if (tid < 256) {
    float s = *(float*)(smem + WG_OFF + tid * 4) +
              *(float*)(smem + WG_OFF + (256 + tid) * 4);
    float s2 = *(float*)(smem + WG_OFF + 2048 + tid * 4) +
               *(float*)(smem + WG_OFF + 2048 + (256 + tid) * 4);
    ps[b * 256 + tid] = s;
    ps2[b * 256 + tid] = s2;
  }
}

// ---------------------------------------------------------------- kernel D2
__global__ __launch_bounds__(256) void bn_finalize_kernel(
    const float* __restrict__ ps, const float* __restrict__ ps2,
    const float* __restrict__ gamma, const float* __restrict__ beta,
    float* __restrict__ scale, float* __restrict__ shift) {
  const int c = threadIdx.x;
  float s = 0.f, s2 = 0.f;
  for (int g = 0; g < 512; ++g) { s += ps[g * 256 + c]; s2 += ps2[g * 256 + c]; }
  const float mean = s * (1.f / (float)M_);
  const float var = s2 * (1.f / (float)M_) - mean * mean;
  const float rstd = rsqrtf(var + 1e-5f);
  scale[c] = gamma[c] * rstd;
  shift[c] = beta[c] - mean * gamma[c] * rstd;
}

// ---------------------------------------------------------------- kernel E
// y = relu(outNC*scale + shift + x), transposed back to [B][C][81] via LDS.
__global__ __launch_bounds__(256) void bn_apply_kernel(
    const ushort* __restrict__ outNC, const float* __restrict__ x,
    const float* __restrict__ scale, const float* __restrict__ shift,
    float* __restrict__ y) {
  __shared__ float t[N_ * 65];
  const int b = blockIdx.x, tid = threadIdx.x;
  for (int c0 = 0; c0 < 256; c0 += 64) {
    __syncthreads();
    for (int e = tid; e < N_ * 64; e += 256) {
      int n = e >> 6, c = e & 63;
      t[n * 65 + c] = bf2f(outNC[((size_t)b * N_ + n) * 256 + c0 + c]);
    }
    __syncthreads();
    for (int f = tid; f < 64 * N_; f += 256) {
      int c = f / N_, n = f - c * N_;
      float o = t[n * 65 + c];
      size_t gi = (size_t)b * (C_ * N_) + (size_t)(c0 + c) * N_ + n;
      float bn = o * scale[c0 + c] + shift[c0 + c];
      float v = bn + x[gi];
      y[gi] = v > 0.f ? v : 0.f;
    }
  }
}

// ----------------------------------------------------------------
extern "C" void kernel_launch(void* const* d_in, const int* in_sizes, int n_in,
                              void* d_out, int out_size, void* d_ws,
                              size_t ws_size, hipStream_t stream) {
  const float* x     = (const float*)d_in[0];
  const float* wq    = (const float*)d_in[1];
  const float* bq    = (const float*)d_in[2];
  const float* wk    = (const float*)d_in[3];
  const float* bk    = (const float*)d_in[4];
  const float* wv    = (const float*)d_in[5];
  const float* bv    = (const float*)d_in[6];
  const float* a     = (const float*)d_in[7];
  const float* gamma = (const float*)d_in[8];
  const float* beta  = (const float*)d_in[9];
  float* out = (float*)d_out;

  ushort* outNC = (ushort*)d_ws;                        // 21.2 MB (aliases
  char*   hlbuf = (char*)d_ws;                          //  hlbuf 48 MB; hlbuf
                                                        //  consumed by knn)
  ushort* tokb = (ushort*)d_ws + (size_t)M_ * 768;      // at 63.7 MB mark
  ushort* wcat = tokb + (size_t)M_ * 256;               // 768*256 bf16
  float*  bcat = (float*)(wcat + 768 * 256);            // 768 f32
  int*    kidx = (int*)(bcat + 768);                    // M*9 int
  float*  ps   = (float*)(kidx + (size_t)M_ * KNN);     // 512*256
  float*  ps2  = ps + 512 * 256;                        // 512*256
  float*  scale = ps2 + 512 * 256;                      // 256
  float*  shift = scale + 256;                          // 256

  split_kernel<<<8 * B_, 256, 0, stream>>>(x, tokb, hlbuf);
  knn_kernel<<<B_, 256, 0, stream>>>(hlbuf, kidx);
  pack_w_kernel<<<768, 256, 0, stream>>>(wq, bq, wk, bk, wv, bv, wcat, bcat);
  fused_kernel<<<B_, 768, 0, stream>>>(tokb, wcat, bcat, kidx, a,
                                       outNC, ps, ps2);
  bn_finalize_kernel<<<1, 256, 0, stream>>>(ps, ps2, gamma, beta, scale, shift);
  bn_apply_kernel<<<B_, 256, 0, stream>>>(outNC, x, scale, shift, out);
}

// Round 12
// 165.966 us; speedup vs baseline: 1.1836x; 1.1836x over previous
//
#include <hip/hip_runtime.h>
#include <hip/hip_bf16.h>

#define B_   512
#define C_   256
#define N_   81                 // tokens per batch (9x9)
#define M_   (B_ * N_)          // 41472
#define KNN  9

typedef __attribute__((ext_vector_type(8))) short short8;
typedef __attribute__((ext_vector_type(4))) float f32x4;
typedef __attribute__((ext_vector_type(4))) ushort u16x4;

#define GLD16(g, l) __builtin_amdgcn_global_load_lds(                      \
    (const __attribute__((address_space(1))) void*)(g),                    \
    (__attribute__((address_space(3))) void*)(l), 16, 0, 0)

__device__ __forceinline__ float bf2f(ushort u) {
  union { uint i; float f; } c; c.i = (uint)u << 16; return c.f;
}
__device__ __forceinline__ ushort f2bf(float f) {
  __hip_bfloat16 h = __float2bfloat16(f); return *(ushort*)&h;
}

// ---------------------------------------------------------------- kernel A1
// blocks 0..4095: transpose/split per (batch, 32-ch chunk) -> pre-swizzled
// 12288-B hl image (rows 81..95 zeroed) + tokb hi rows.
// blocks 4096..4863: weight pack (wq|wk|wv -> bf16 wcat, biases -> bcat).
__global__ __launch_bounds__(256) void split_kernel(
    const float* __restrict__ x, ushort* __restrict__ tokb,
    char* __restrict__ hlbuf,
    const float* __restrict__ wq, const float* __restrict__ bq,
    const float* __restrict__ wk, const float* __restrict__ bk,
    const float* __restrict__ wv, const float* __restrict__ bv,
    ushort* __restrict__ wcat, float* __restrict__ bcat) {
  __shared__ __align__(16) float raw[32 * 81];   // 10368 B
  const int bid = blockIdx.x;
  const int tid = threadIdx.x;
  if (bid >= 4096) {             // ---- weight pack path
    const int j = bid - 4096, c = tid;
    const int sel = j >> 8, jr = j & 255;
    const float* W  = sel == 0 ? wq : (sel == 1 ? wk : wv);
    const float* Bb = sel == 0 ? bq : (sel == 1 ? bk : bv);
    wcat[(size_t)j * 256 + c] = f2bf(W[jr * 256 + c]);
    if (c == 0) bcat[j] = Bb[jr];
    return;
  }
  const int b = bid >> 3, ch = bid & 7;
  const float* src = x + (size_t)b * (C_ * N_) + ch * 32 * N_;
#pragma unroll
  for (int it = 0; it < 3; ++it) {
    int e4 = tid + it * 256;
    if (e4 < 648) *(f32x4*)&raw[e4 * 4] = *(const f32x4*)&src[e4 * 4];
  }
  char* dst = hlbuf + (size_t)bid * 12288;
  for (int p = tid; p < 480; p += 256)
    *(uint*)(dst + (81 + p / 32) * 128 + (p & 31) * 4) = 0u;
  __syncthreads();
#pragma unroll
  for (int it = 0; it < 6; ++it) {
    int p = tid + it * 256;
    if (p < 1296) {
      int n = p >> 4, q = p & 15;
      float v0 = raw[(2 * q) * N_ + n];
      float v1 = raw[(2 * q + 1) * N_ + n];
      __hip_bfloat16 h0 = __float2bfloat16(v0);
      __hip_bfloat16 h1 = __float2bfloat16(v1);
      float r0 = v0 - __bfloat162float(h0);
      float r1 = v1 - __bfloat162float(h1);
      __hip_bfloat16 g0 = __float2bfloat16(r0);
      __hip_bfloat16 g1 = __float2bfloat16(r1);
      uint hp = (uint)(*(ushort*)&h0) | ((uint)(*(ushort*)&h1) << 16);
      uint lp = (uint)(*(ushort*)&g0) | ((uint)(*(ushort*)&g1) << 16);
      int off = (((q >> 2) << 4) ^ (((n >> 1) & 3) << 4)) + ((q & 3) << 2);
      int hs = (n & 1) << 6;
      *(uint*)(dst + n * 128 + hs + off) = hp;
      *(uint*)(dst + n * 128 + (hs ^ 64) + off) = lp;
      *(uint*)&tokb[((size_t)(b * N_ + n)) * 256 + ch * 32 + 2 * q] = hp;
    }
  }
}

// ---------------------------------------------------------------- kernel A2
// Per batch: double-buffered global_load_lds of the 8 pre-swizzled hl
// chunks (counted vmcnt(3)), 4-term MFMA gram, diag from G, 9-smallest
// selection. (verified r7-r9)
__global__ __launch_bounds__(256) void knn_kernel(
    const char* __restrict__ hlbuf, int* __restrict__ knn_idx) {
  __shared__ __align__(16) char smem[31488];     // bufs 2x12288; G overlay
  __shared__ float sqv[96];
  const int b = blockIdx.x;
  const int tid = threadIdx.x;
  const int w = tid >> 6, lane = tid & 63;
  const int wr = w >> 1, wc = w & 1;              // 48x48 quadrant of G
  const int l15 = lane & 15;
  const int g16 = lane >> 4;                      // 16B k-group 0..3

  const char* srcb = hlbuf + (size_t)b * 8 * 12288;

#pragma unroll
  for (int it = 0; it < 3; ++it) {
    int idx = it * 256 + tid;
    GLD16(srcb + idx * 16, smem + idx * 16);
  }

  f32x4 acc[3][3];
#pragma unroll
  for (int i = 0; i < 3; ++i)
#pragma unroll
    for (int j = 0; j < 3; ++j) acc[i][j] = {0.f, 0.f, 0.f, 0.f};

#pragma unroll
  for (int ch = 0; ch < 8; ++ch) {
    char* cur = smem + (ch & 1) * 12288;
    char* nxt = smem + ((ch + 1) & 1) * 12288;
    if (ch < 7) {
      const char* s2 = srcb + (size_t)(ch + 1) * 12288;
#pragma unroll
      for (int it = 0; it < 3; ++it) {
        int idx = it * 256 + tid;
        GLD16(s2 + idx * 16, nxt + idx * 16);
      }
      asm volatile("s_waitcnt vmcnt(3)" ::: "memory");   // cur's 3 done
    } else {
      asm volatile("s_waitcnt vmcnt(0)" ::: "memory");
    }
    __builtin_amdgcn_s_barrier();
    __builtin_amdgcn_sched_barrier(0);
    short8 ah[3], al[3], bh[3], bl[3];
#pragma unroll
    for (int i = 0; i < 3; ++i) {
      int ra = wr * 48 + i * 16 + l15;
      int basea = ra * 128 + ((g16 << 4) ^ (((ra >> 1) & 3) << 4));
      int hsa = (ra & 1) << 6;
      ah[i] = *(const short8*)(cur + basea + hsa);
      al[i] = *(const short8*)(cur + basea + (hsa ^ 64));
      int rb = wc * 48 + i * 16 + l15;
      int baseb = rb * 128 + ((g16 << 4) ^ (((rb >> 1) & 3) << 4));
      int hsb = (rb & 1) << 6;
      bh[i] = *(const short8*)(cur + baseb + hsb);
      bl[i] = *(const short8*)(cur + baseb + (hsb ^ 64));
    }
#pragma unroll
    for (int i = 0; i < 3; ++i)
#pragma unroll
      for (int j = 0; j < 3; ++j) {
        acc[i][j] = __builtin_amdgcn_mfma_f32_16x16x32_bf16(
            ah[i], bh[j], acc[i][j], 0, 0, 0);
        acc[i][j] = __builtin_amdgcn_mfma_f32_16x16x32_bf16(
            ah[i], bl[j], acc[i][j], 0, 0, 0);
        acc[i][j] = __builtin_amdgcn_mfma_f32_16x16x32_bf16(
            al[i], bh[j], acc[i][j], 0, 0, 0);
        acc[i][j] = __builtin_amdgcn_mfma_f32_16x16x32_bf16(
            al[i], bl[j], acc[i][j], 0, 0, 0);
      }
    __builtin_amdgcn_sched_barrier(0);
    __builtin_amdgcn_s_barrier();   // reads done before next GLD overwrite
  }
  float* G = (float*)smem;
#pragma unroll
  for (int i = 0; i < 3; ++i) {
    const int row0 = wr * 48 + i * 16 + ((lane >> 4) << 2);
#pragma unroll
    for (int j = 0; j < 3; ++j) {
      const int col = wc * 48 + j * 16 + l15;
#pragma unroll
      for (int reg = 0; reg < 4; ++reg) {
        const int row = row0 + reg;
        if (row < N_) G[row * 97 + col] = acc[i][j][reg];
      }
    }
  }
  __syncthreads();
  if (tid < N_) sqv[tid] = G[tid * 97 + tid];   // diag = |token|^2 (4-term)
  __syncthreads();
  if (tid < N_) {
    const int n = tid;
    const float sn = sqv[n];
    const float* grow = &G[n * 97];
    float bd[KNN]; int bi[KNN];
#pragma unroll
    for (int k = 0; k < KNN; ++k) { bd[k] = 3.4e38f; bi[k] = 0; }
    for (int m = 0; m < N_; ++m) {
      float d2 = sn + sqv[m] - 2.f * grow[m];
      float wv = bd[0]; int wi = 0;
#pragma unroll
      for (int k = 1; k < KNN; ++k) {
        bool g_ = bd[k] > wv;
        wv = g_ ? bd[k] : wv;
        wi = g_ ? k : wi;
      }
      bool repl = d2 < wv;
#pragma unroll
      for (int k = 0; k < KNN; ++k) {
        bool here = repl & (wi == k);
        bd[k] = here ? d2 : bd[k];
        bi[k] = here ? m : bi[k];
      }
    }
#pragma unroll
    for (int k = 0; k < KNN; ++k)
      knn_idx[((size_t)b * N_ + n) * KNN + k] = bi[k];
  }
}

// ---------------------------------------------------------------- kernel B
// bf16 MFMA GEMM: qkvb[M][768] = tok[M][256] @ wcat^T + bcat (bf16 out).
// XCD-chunked, jt-inner 1D grid: xcd=bid&7 owns m-tiles [xcd*41, xcd*41+41);
// the 6 j-tiles of one m-tile issue consecutively on that XCD -> A-tile is
// fetched from HBM once and L2-hits 5x (was 6x HBM: grid (324,6) rotated
// the m->XCD map between jt sweeps since 324%8!=0).
__global__ __launch_bounds__(256) void qkv_mfma_kernel(
    const ushort* __restrict__ tokb, const ushort* __restrict__ wcat,
    const float* __restrict__ bcat, ushort* __restrict__ qkvb) {
  __shared__ ushort At[128 * 64];   // 16 KB, row-major [r][k], swizzled
  __shared__ ushort Bt[128 * 64];   // 16 KB
  const int bid = blockIdx.x;       // grid 1968 = 8 * 41 * 6
  const int xcd = bid & 7, li = bid >> 3;      // li 0..245
  const int mt = xcd * 41 + li / 6;            // m-tile 0..327
  if (mt >= 324) return;                       // 24 pad blocks exit
  const int m0 = mt * 128;
  const int j0 = (li % 6) * 128;
  const int tid = threadIdx.x;
  const int w = tid >> 6, lane = tid & 63;
  const int wr = w >> 1, wc = w & 1;

  const char* pA[4]; const char* pB[4]; int oL[4];
#pragma unroll
  for (int it = 0; it < 4; ++it) {
    int o = (it * 256 + tid) * 16;
    int r = o >> 7, cp = o & 127;
    int cl = cp ^ ((r & 7) << 4);
    oL[it] = o;
    pA[it] = (const char*)tokb + ((size_t)(m0 + r) * 256) * 2 + cl;
    pB[it] = (const char*)wcat + ((size_t)(j0 + r) * 256) * 2 + cl;
  }

  f32x4 acc[4][4];
#pragma unroll
  for (int i = 0; i < 4; ++i)
#pragma unroll
    for (int j = 0; j < 4; ++j) acc[i][j] = {0.f, 0.f, 0.f, 0.f};

  const int l15 = lane & 15;
  const int sw = (lane & 7) << 4;
  const int kgrp = (lane >> 4) << 4;

  for (int k0 = 0; k0 < 256; k0 += 64) {
    __syncthreads();
#pragma unroll
    for (int it = 0; it < 4; ++it) {
      GLD16(pA[it] + k0 * 2, (char*)At + oL[it]);
      GLD16(pB[it] + k0 * 2, (char*)Bt + oL[it]);
    }
    __syncthreads();
#pragma unroll
    for (int kk = 0; kk < 2; ++kk) {
      const int cb = (kk * 64 + kgrp) ^ sw;
      short8 am[4], bn[4];
#pragma unroll
      for (int i = 0; i < 4; ++i) {
        const int ra = wr * 64 + i * 16 + l15;
        am[i] = *(const short8*)((const char*)At + ra * 128 + cb);
        const int rb = wc * 64 + i * 16 + l15;
        bn[i] = *(const short8*)((const char*)Bt + rb * 128 + cb);
      }
#pragma unroll
      for (int i = 0; i < 4; ++i)
#pragma unroll
        for (int j = 0; j < 4; ++j)
          acc[i][j] = __builtin_amdgcn_mfma_f32_16x16x32_bf16(
              am[i], bn[j], acc[i][j], 0, 0, 0);
    }
  }

  // epilogue -> bf16 qkv
#pragma unroll
  for (int j = 0; j < 4; ++j) {
    const int colj = j0 + wc * 64 + j * 16 + l15;
    const float bs = bcat[colj];
#pragma unroll
    for (int i = 0; i < 4; ++i) {
      const int rowm = m0 + wr * 64 + i * 16 + ((lane >> 4) << 2);
#pragma unroll
      for (int reg = 0; reg < 4; ++reg)
        qkvb[(size_t)(rowm + reg) * 768 + colj] = f2bf(acc[i][j][reg] + bs);
    }
  }
}

// ---------------------------------------------------------------- kernel C
// One WAVE per token, bf16 q/k/v (8B per lane loads). Writes bf16 output
// in place into the q-slot of qkvb.
__global__ __launch_bounds__(256) void attn_kernel(
    const ushort* __restrict__ qkvc, const int* __restrict__ knn_idx,
    const float* __restrict__ a, ushort* __restrict__ qkvb) {
  const int nwg = M_ / 4;                    // 10368 = 8 * 1296
  const int bid = blockIdx.x;
  const int swz = (bid & 7) * (nwg / 8) + (bid >> 3);  // XCD-contiguous
  const int w = threadIdx.x >> 6, lane = threadIdx.x & 63;
  const int m = swz * 4 + w;                 // this wave's token
  const int b = m / N_;
  const int bbase = b * N_;

  const u16x4 qu = *(const u16x4*)&qkvc[(size_t)m * 768 + lane * 4];
  const f32x4 a4 = *(const f32x4*)&a[lane * 4];
  float q4[4];
#pragma unroll
  for (int u = 0; u < 4; ++u) q4[u] = bf2f(qu[u]);

  float sc[KNN];
  int nb[KNN];
#pragma unroll
  for (int k = 0; k < KNN; ++k) {
    int nbk = knn_idx[(size_t)m * KNN + k];
    nbk = __builtin_amdgcn_readfirstlane(nbk);
    nb[k] = nbk;
    const ushort* krow = qkvc + (size_t)(bbase + nbk) * 768 + 256;
    const u16x4 ku = *(const u16x4*)&krow[lane * 4];
    float p = 0.f;
#pragma unroll
    for (int u = 0; u < 4; ++u) {
      float t = q4[u] + bf2f(ku[u]);
      t = fmaxf(t, 0.2f * t);                // leaky_relu(t, 0.2)
      p = __builtin_fmaf(t, a4[u], p);
    }
    p += __shfl_xor(p, 1, 16);
    p += __shfl_xor(p, 2, 16);
    p += __shfl_xor(p, 4, 16);
    p += __shfl_xor(p, 8, 16);
    sc[k] = p;
  }
  float mx = sc[0];
#pragma unroll
  for (int k = 1; k < KNN; ++k) mx = fmaxf(mx, sc[k]);
  float s = 0.f;
#pragma unroll
  for (int k = 0; k < KNN; ++k) {
    sc[k] = __builtin_amdgcn_exp2f((sc[k] - mx) * 1.44269504f);
    s += sc[k];
  }
  const float inv = __builtin_amdgcn_rcpf(s);
  f32x4 acc = {0.f, 0.f, 0.f, 0.f};
#pragma unroll
  for (int k = 0; k < KNN; ++k) {
    const ushort* vrow = qkvc + (size_t)(bbase + nb[k]) * 768 + 512;
    const u16x4 vu = *(const u16x4*)&vrow[lane * 4];
    const float wk_ = sc[k] * inv;
#pragma unroll
    for (int u = 0; u < 4; ++u)
      acc[u] = __builtin_fmaf(wk_, bf2f(vu[u]), acc[u]);
  }
  u16x4 o;
#pragma unroll
  for (int u = 0; u < 4; ++u) o[u] = f2bf(acc[u]);
  *(u16x4*)&qkvb[(size_t)m * 768 + lane * 4] = o;   // overwrite own q-slot
}

// ---------------------------------------------------------------- kernel D
// Deterministic two-stage BN stats over bf16 q-slots (stride 768).
__global__ __launch_bounds__(256) void bn_partial_kernel(
    const ushort* __restrict__ qkvb, float* __restrict__ ps,
    float* __restrict__ ps2) {
  const int g = blockIdx.x, c = threadIdx.x;
  float s = 0.f, s2 = 0.f;
  for (int r = 0; r < M_ / 256; ++r) {
    float v = bf2f(qkvb[((size_t)g * (M_ / 256) + r) * 768 + c]);
    s += v; s2 += v * v;
  }
  ps[g * 256 + c] = s;
  ps2[g * 256 + c] = s2;
}

__global__ __launch_bounds__(256) void bn_finalize_kernel(
    const float* __restrict__ ps, const float* __restrict__ ps2,
    const float* __restrict__ gamma, const float* __restrict__ beta,
    float* __restrict__ scale, float* __restrict__ shift) {
  const int c = threadIdx.x;
  float s = 0.f, s2 = 0.f;
  for (int g = 0; g < 256; ++g) { s += ps[g * 256 + c]; s2 += ps2[g * 256 + c]; }
  const float mean = s * (1.f / (float)M_);
  const float var = s2 * (1.f / (float)M_) - mean * mean;
  const float rstd = rsqrtf(var + 1e-5f);
  scale[c] = gamma[c] * rstd;
  shift[c] = beta[c] - mean * gamma[c] * rstd;
}

// ---------------------------------------------------------------- kernel E
// y = relu(attn*scale + shift + x), transposed back to [B][C][81] via LDS.
__global__ __launch_bounds__(256) void bn_apply_kernel(
    const ushort* __restrict__ qkvb, const float* __restrict__ x,
    const float* __restrict__ scale, const float* __restrict__ shift,
    float* __restrict__ y) {
  __shared__ float t[N_ * 65];
  const int b = blockIdx.x, tid = threadIdx.x;
  for (int c0 = 0; c0 < 256; c0 += 64) {
    __syncthreads();
    for (int e = tid; e < N_ * 64; e += 256) {
      int n = e >> 6, c = e & 63;
      t[n * 65 + c] = bf2f(qkvb[((size_t)b * N_ + n) * 768 + c0 + c]);
    }
    __syncthreads();
    for (int f = tid; f < 64 * N_; f += 256) {
      int c = f / N_, n = f - c * N_;
      float o = t[n * 65 + c];
      size_t gi = (size_t)b * (C_ * N_) + (size_t)(c0 + c) * N_ + n;
      float bn = o * scale[c0 + c] + shift[c0 + c];
      float v = bn + x[gi];
      y[gi] = v > 0.f ? v : 0.f;
    }
  }
}

// ----------------------------------------------------------------
extern "C" void kernel_launch(void* const* d_in, const int* in_sizes, int n_in,
                              void* d_out, int out_size, void* d_ws,
                              size_t ws_size, hipStream_t stream) {
  const float* x     = (const float*)d_in[0];
  const float* wq    = (const float*)d_in[1];
  const float* bq    = (const float*)d_in[2];
  const float* wk    = (const float*)d_in[3];
  const float* bk    = (const float*)d_in[4];
  const float* wv    = (const float*)d_in[5];
  const float* bv    = (const float*)d_in[6];
  const float* a     = (const float*)d_in[7];
  const float* gamma = (const float*)d_in[8];
  const float* beta  = (const float*)d_in[9];
  float* out = (float*)d_out;

  ushort* qkvb = (ushort*)d_ws;                         // M*768 bf16 (63.7MB)
  char*   hlbuf = (char*)qkvb;                          // 48 MB alias,
                                                        // consumed pre-qkv
  ushort* tokb = qkvb + (size_t)M_ * 768;               // M*256 bf16
  ushort* wcat = tokb + (size_t)M_ * 256;               // 768*256 bf16
  float*  bcat = (float*)(wcat + 768 * 256);            // 768 f32
  int*    kidx = (int*)(bcat + 768);                    // M*9 int
  float*  ps   = (float*)(kidx + (size_t)M_ * KNN);     // 256*256
  float*  ps2  = ps + 256 * 256;                        // 256*256
  float*  scale = ps2 + 256 * 256;                      // 256
  float*  shift = scale + 256;                          // 256

  split_kernel<<<4096 + 768, 256, 0, stream>>>(
      x, tokb, hlbuf, wq, bq, wk, bk, wv, bv, wcat, bcat);
  knn_kernel<<<B_, 256, 0, stream>>>(hlbuf, kidx);
  qkv_mfma_kernel<<<1968, 256, 0, stream>>>(tokb, wcat, bcat, qkvb);
  attn_kernel<<<M_ / 4, 256, 0, stream>>>(qkvb, kidx, a, qkvb);
  bn_partial_kernel<<<256, 256, 0, stream>>>(qkvb, ps, ps2);
  bn_finalize_kernel<<<1, 256, 0, stream>>>(ps, ps2, gamma, beta, scale, shift);
  bn_apply_kernel<<<B_, 256, 0, stream>>>(qkvb, x, scale, shift, out);
}

// Round 13
// 160.833 us; speedup vs baseline: 1.2214x; 1.0319x over previous
//
#include <hip/hip_runtime.h>
#include <hip/hip_bf16.h>

#define B_   512
#define C_   256
#define N_   81                 // tokens per batch (9x9)
#define M_   (B_ * N_)          // 41472
#define KNN  9

typedef __attribute__((ext_vector_type(8))) short short8;
typedef __attribute__((ext_vector_type(4))) float f32x4;
typedef __attribute__((ext_vector_type(4))) ushort u16x4;

#define GLD16(g, l) __builtin_amdgcn_global_load_lds(                      \
    (const __attribute__((address_space(1))) void*)(g),                    \
    (__attribute__((address_space(3))) void*)(l), 16, 0, 0)

__device__ __forceinline__ float bf2f(ushort u) {
  union { uint i; float f; } c; c.i = (uint)u << 16; return c.f;
}
__device__ __forceinline__ ushort f2bf(float f) {
  __hip_bfloat16 h = __float2bfloat16(f); return *(ushort*)&h;
}

// ---------------------------------------------------------------- kernel A1
// blocks 0..4095: transpose/split per (batch, 32-ch chunk) -> tokb hi rows
// (linear [m][256] bf16) + lobuf lo image (6144 B per (b,ch), pre-swizzled:
// lo pair q of row n at n*64 + (((q>>2)<<4) ^ (((n>>1)&3)<<4)) + (q&3)*4).
// hi is NOT duplicated anymore -- knn stages it from tokb directly.
// blocks 4096..4863: weight pack (wq|wk|wv -> bf16 wcat, biases -> bcat).
__global__ __launch_bounds__(256) void split_kernel(
    const float* __restrict__ x, ushort* __restrict__ tokb,
    char* __restrict__ lobuf,
    const float* __restrict__ wq, const float* __restrict__ bq,
    const float* __restrict__ wk, const float* __restrict__ bk,
    const float* __restrict__ wv, const float* __restrict__ bv,
    ushort* __restrict__ wcat, float* __restrict__ bcat) {
  __shared__ __align__(16) float raw[32 * 81];   // 10368 B
  const int bid = blockIdx.x;
  const int tid = threadIdx.x;
  if (bid >= 4096) {             // ---- weight pack path
    const int j = bid - 4096, c = tid;
    const int sel = j >> 8, jr = j & 255;
    const float* W  = sel == 0 ? wq : (sel == 1 ? wk : wv);
    const float* Bb = sel == 0 ? bq : (sel == 1 ? bk : bv);
    wcat[(size_t)j * 256 + c] = f2bf(W[jr * 256 + c]);
    if (c == 0) bcat[j] = Bb[jr];
    return;
  }
  const int b = bid >> 3, ch = bid & 7;
  const float* src = x + (size_t)b * (C_ * N_) + ch * 32 * N_;
#pragma unroll
  for (int it = 0; it < 3; ++it) {
    int e4 = tid + it * 256;
    if (e4 < 648) *(f32x4*)&raw[e4 * 4] = *(const f32x4*)&src[e4 * 4];
  }
  char* dst = lobuf + (size_t)bid * 6144;
  __syncthreads();
#pragma unroll
  for (int it = 0; it < 6; ++it) {
    int p = tid + it * 256;
    if (p < 1296) {
      int n = p >> 4, q = p & 15;
      float v0 = raw[(2 * q) * N_ + n];
      float v1 = raw[(2 * q + 1) * N_ + n];
      __hip_bfloat16 h0 = __float2bfloat16(v0);
      __hip_bfloat16 h1 = __float2bfloat16(v1);
      float r0 = v0 - __bfloat162float(h0);
      float r1 = v1 - __bfloat162float(h1);
      __hip_bfloat16 g0 = __float2bfloat16(r0);
      __hip_bfloat16 g1 = __float2bfloat16(r1);
      uint hp = (uint)(*(ushort*)&h0) | ((uint)(*(ushort*)&h1) << 16);
      uint lp = (uint)(*(ushort*)&g0) | ((uint)(*(ushort*)&g1) << 16);
      int off = (((q >> 2) << 4) ^ (((n >> 1) & 3) << 4)) + ((q & 3) << 2);
      *(uint*)(dst + n * 64 + off) = lp;
      *(uint*)&tokb[((size_t)(b * N_ + n)) * 256 + ch * 32 + 2 * q] = hp;
    }
  }
}

// ---------------------------------------------------------------- kernel A2
// Per batch: double-buffered staging (counted vmcnt(3)). HI staged straight
// from tokb with pre-swizzled per-lane SOURCE (g = gp ^ ((n>>1)&3)) so the
// LDS image matches the MFMA read swizzle bit-for-bit; LO copied linearly
// from the pre-swizzled lobuf. Rows 81..95 read garbage (next batch / wcat)
// -- harmless: MFMA element (r,c) only mixes row r of A and col c of B, and
// rows/cols >= 81 are never stored or read by the selection.
// 4-term MFMA gram, diag from G, 9-smallest selection (bit-identical to r12).
__global__ __launch_bounds__(256) void knn_kernel(
    const ushort* __restrict__ tokb, const char* __restrict__ lobuf,
    int* __restrict__ knn_idx) {
  __shared__ __align__(16) char smem[31488];     // bufs 2x(HI 6144|LO 6144)
  __shared__ float sqv[96];
  const int b = blockIdx.x;
  const int tid = threadIdx.x;
  const int w = tid >> 6, lane = tid & 63;
  const int wr = w >> 1, wc = w & 1;              // 48x48 quadrant of G
  const int l15 = lane & 15;
  const int g16 = lane >> 4;                      // 16B k-group 0..3

  const char* tb = (const char*)(tokb + (size_t)b * N_ * 256);  // 81 x 512B
  const char* lb = lobuf + (size_t)b * 8 * 6144;

  // prologue: stage chunk 0 -> buf0
#pragma unroll
  for (int it = 0; it < 3; ++it) {
    int idx = it * 256 + tid;
    if (idx < 384) {
      int n = idx >> 2, gp = idx & 3;
      int g = gp ^ ((n >> 1) & 3);
      GLD16(tb + (size_t)n * 512 + (g << 4), smem + idx * 16);
    } else {
      GLD16(lb + (idx - 384) * 16, smem + idx * 16);
    }
  }

  f32x4 acc[3][3];
#pragma unroll
  for (int i = 0; i < 3; ++i)
#pragma unroll
    for (int j = 0; j < 3; ++j) acc[i][j] = {0.f, 0.f, 0.f, 0.f};

#pragma unroll
  for (int ch = 0; ch < 8; ++ch) {
    char* cur = smem + (ch & 1) * 12288;
    char* nxt = smem + ((ch + 1) & 1) * 12288;
    if (ch < 7) {
#pragma unroll
      for (int it = 0; it < 3; ++it) {
        int idx = it * 256 + tid;
        if (idx < 384) {
          int n = idx >> 2, gp = idx & 3;
          int g = gp ^ ((n >> 1) & 3);
          GLD16(tb + (size_t)n * 512 + (ch + 1) * 64 + (g << 4),
                nxt + idx * 16);
        } else {
          GLD16(lb + (size_t)(ch + 1) * 6144 + (idx - 384) * 16,
                nxt + idx * 16);
        }
      }
      asm volatile("s_waitcnt vmcnt(3)" ::: "memory");   // cur's 3 done
    } else {
      asm volatile("s_waitcnt vmcnt(0)" ::: "memory");
    }
    __builtin_amdgcn_s_barrier();
    __builtin_amdgcn_sched_barrier(0);
    short8 ah[3], al[3], bh[3], bl[3];
#pragma unroll
    for (int i = 0; i < 3; ++i) {
      int ra = wr * 48 + i * 16 + l15;
      int oa = ra * 64 + ((g16 << 4) ^ (((ra >> 1) & 3) << 4));
      ah[i] = *(const short8*)(cur + oa);
      al[i] = *(const short8*)(cur + 6144 + oa);
      int rb = wc * 48 + i * 16 + l15;
      int ob = rb * 64 + ((g16 << 4) ^ (((rb >> 1) & 3) << 4));
      bh[i] = *(const short8*)(cur + ob);
      bl[i] = *(const short8*)(cur + 6144 + ob);
    }
#pragma unroll
    for (int i = 0; i < 3; ++i)
#pragma unroll
      for (int j = 0; j < 3; ++j) {
        acc[i][j] = __builtin_amdgcn_mfma_f32_16x16x32_bf16(
            ah[i], bh[j], acc[i][j], 0, 0, 0);
        acc[i][j] = __builtin_amdgcn_mfma_f32_16x16x32_bf16(
            ah[i], bl[j], acc[i][j], 0, 0, 0);
        acc[i][j] = __builtin_amdgcn_mfma_f32_16x16x32_bf16(
            al[i], bh[j], acc[i][j], 0, 0, 0);
        acc[i][j] = __builtin_amdgcn_mfma_f32_16x16x32_bf16(
            al[i], bl[j], acc[i][j], 0, 0, 0);
      }
    __builtin_amdgcn_sched_barrier(0);
    __builtin_amdgcn_s_barrier();   // reads done before next GLD overwrite
  }
  float* G = (float*)smem;
#pragma unroll
  for (int i = 0; i < 3; ++i) {
    const int row0 = wr * 48 + i * 16 + ((lane >> 4) << 2);
#pragma unroll
    for (int j = 0; j < 3; ++j) {
      const int col = wc * 48 + j * 16 + l15;
#pragma unroll
      for (int reg = 0; reg < 4; ++reg) {
        const int row = row0 + reg;
        if (row < N_) G[row * 97 + col] = acc[i][j][reg];
      }
    }
  }
  __syncthreads();
  if (tid < N_) sqv[tid] = G[tid * 97 + tid];   // diag = |token|^2 (4-term)
  __syncthreads();
  if (tid < N_) {
    const int n = tid;
    const float sn = sqv[n];
    const float* grow = &G[n * 97];
    float bd[KNN]; int bi[KNN];
#pragma unroll
    for (int k = 0; k < KNN; ++k) { bd[k] = 3.4e38f; bi[k] = 0; }
    for (int m = 0; m < N_; ++m) {
      float d2 = sn + sqv[m] - 2.f * grow[m];
      float wv = bd[0]; int wi = 0;
#pragma unroll
      for (int k = 1; k < KNN; ++k) {
        bool g_ = bd[k] > wv;
        wv = g_ ? bd[k] : wv;
        wi = g_ ? k : wi;
      }
      bool repl = d2 < wv;
#pragma unroll
      for (int k = 0; k < KNN; ++k) {
        bool here = repl & (wi == k);
        bd[k] = here ? d2 : bd[k];
        bi[k] = here ? m : bi[k];
      }
    }
#pragma unroll
    for (int k = 0; k < KNN; ++k)
      knn_idx[((size_t)b * N_ + n) * KNN + k] = bi[k];
  }
}

// ---------------------------------------------------------------- kernel B
// bf16 MFMA GEMM: qkvb[M][768] = tok[M][256] @ wcat^T + bcat (bf16 out).
// XCD-chunked, jt-inner 1D grid (A-tile L2 reuse, verified r12).
__global__ __launch_bounds__(256) void qkv_mfma_kernel(
    const ushort* __restrict__ tokb, const ushort* __restrict__ wcat,
    const float* __restrict__ bcat, ushort* __restrict__ qkvb) {
  __shared__ ushort At[128 * 64];   // 16 KB, row-major [r][k], swizzled
  __shared__ ushort Bt[128 * 64];   // 16 KB
  const int bid = blockIdx.x;       // grid 1968 = 8 * 41 * 6
  const int xcd = bid & 7, li = bid >> 3;      // li 0..245
  const int mt = xcd * 41 + li / 6;            // m-tile 0..327
  if (mt >= 324) return;                       // 24 pad blocks exit
  const int m0 = mt * 128;
  const int j0 = (li % 6) * 128;
  const int tid = threadIdx.x;
  const int w = tid >> 6, lane = tid & 63;
  const int wr = w >> 1, wc = w & 1;

  const char* pA[4]; const char* pB[4]; int oL[4];
#pragma unroll
  for (int it = 0; it < 4; ++it) {
    int o = (it * 256 + tid) * 16;
    int r = o >> 7, cp = o & 127;
    int cl = cp ^ ((r & 7) << 4);
    oL[it] = o;
    pA[it] = (const char*)tokb + ((size_t)(m0 + r) * 256) * 2 + cl;
    pB[it] = (const char*)wcat + ((size_t)(j0 + r) * 256) * 2 + cl;
  }

  f32x4 acc[4][4];
#pragma unroll
  for (int i = 0; i < 4; ++i)
#pragma unroll
    for (int j = 0; j < 4; ++j) acc[i][j] = {0.f, 0.f, 0.f, 0.f};

  const int l15 = lane & 15;
  const int sw = (lane & 7) << 4;
  const int kgrp = (lane >> 4) << 4;

  for (int k0 = 0; k0 < 256; k0 += 64) {
    __syncthreads();
#pragma unroll
    for (int it = 0; it < 4; ++it) {
      GLD16(pA[it] + k0 * 2, (char*)At + oL[it]);
      GLD16(pB[it] + k0 * 2, (char*)Bt + oL[it]);
    }
    __syncthreads();
#pragma unroll
    for (int kk = 0; kk < 2; ++kk) {
      const int cb = (kk * 64 + kgrp) ^ sw;
      short8 am[4], bn[4];
#pragma unroll
      for (int i = 0; i < 4; ++i) {
        const int ra = wr * 64 + i * 16 + l15;
        am[i] = *(const short8*)((const char*)At + ra * 128 + cb);
        const int rb = wc * 64 + i * 16 + l15;
        bn[i] = *(const short8*)((const char*)Bt + rb * 128 + cb);
      }
#pragma unroll
      for (int i = 0; i < 4; ++i)
#pragma unroll
        for (int j = 0; j < 4; ++j)
          acc[i][j] = __builtin_amdgcn_mfma_f32_16x16x32_bf16(
              am[i], bn[j], acc[i][j], 0, 0, 0);
    }
  }

  // epilogue -> bf16 qkv
#pragma unroll
  for (int j = 0; j < 4; ++j) {
    const int colj = j0 + wc * 64 + j * 16 + l15;
    const float bs = bcat[colj];
#pragma unroll
    for (int i = 0; i < 4; ++i) {
      const int rowm = m0 + wr * 64 + i * 16 + ((lane >> 4) << 2);
#pragma unroll
      for (int reg = 0; reg < 4; ++reg)
        qkvb[(size_t)(rowm + reg) * 768 + colj] = f2bf(acc[i][j][reg] + bs);
    }
  }
}

// ---------------------------------------------------------------- kernel C
// One WAVE per token, bf16 q/k/v. kidx via ONE lane-parallel load (lane<9)
// + v_readlane broadcast (was 9x64 redundant loads + readfirstlane).
// Writes bf16 output in place into the q-slot of qkvb.
__global__ __launch_bounds__(256) void attn_kernel(
    const ushort* __restrict__ qkvc, const int* __restrict__ knn_idx,
    const float* __restrict__ a, ushort* __restrict__ qkvb) {
  const int nwg = M_ / 4;                    // 10368 = 8 * 1296
  const int bid = blockIdx.x;
  const int swz = (bid & 7) * (nwg / 8) + (bid >> 3);  // XCD-contiguous
  const int w = threadIdx.x >> 6, lane = threadIdx.x & 63;
  const int m = swz * 4 + w;                 // this wave's token
  const int b = m / N_;
  const int bbase = b * N_;

  int nbk_l = 0;
  if (lane < KNN) nbk_l = knn_idx[(size_t)m * KNN + lane];

  const u16x4 qu = *(const u16x4*)&qkvc[(size_t)m * 768 + lane * 4];
  const f32x4 a4 = *(const f32x4*)&a[lane * 4];
  float q4[4];
#pragma unroll
  for (int u = 0; u < 4; ++u) q4[u] = bf2f(qu[u]);

  float sc[KNN];
  int nb[KNN];
#pragma unroll
  for (int k = 0; k < KNN; ++k) {
    const int nbk = __builtin_amdgcn_readlane(nbk_l, k);
    nb[k] = nbk;
    const ushort* krow = qkvc + (size_t)(bbase + nbk) * 768 + 256;
    const u16x4 ku = *(const u16x4*)&krow[lane * 4];
    float p = 0.f;
#pragma unroll
    for (int u = 0; u < 4; ++u) {
      float t = q4[u] + bf2f(ku[u]);
      t = fmaxf(t, 0.2f * t);                // leaky_relu(t, 0.2)
      p = __builtin_fmaf(t, a4[u], p);
    }
    p += __shfl_xor(p, 1, 16);
    p += __shfl_xor(p, 2, 16);
    p += __shfl_xor(p, 4, 16);
    p += __shfl_xor(p, 8, 16);
    sc[k] = p;
  }
  float mx = sc[0];
#pragma unroll
  for (int k = 1; k < KNN; ++k) mx = fmaxf(mx, sc[k]);
  float s = 0.f;
#pragma unroll
  for (int k = 0; k < KNN; ++k) {
    sc[k] = __builtin_amdgcn_exp2f((sc[k] - mx) * 1.44269504f);
    s += sc[k];
  }
  const float inv = __builtin_amdgcn_rcpf(s);
  f32x4 acc = {0.f, 0.f, 0.f, 0.f};
#pragma unroll
  for (int k = 0; k < KNN; ++k) {
    const ushort* vrow = qkvc + (size_t)(bbase + nb[k]) * 768 + 512;
    const u16x4 vu = *(const u16x4*)&vrow[lane * 4];
    const float wk_ = sc[k] * inv;
#pragma unroll
    for (int u = 0; u < 4; ++u)
      acc[u] = __builtin_fmaf(wk_, bf2f(vu[u]), acc[u]);
  }
  u16x4 o;
#pragma unroll
  for (int u = 0; u < 4; ++u) o[u] = f2bf(acc[u]);
  *(u16x4*)&qkvb[(size_t)m * 768 + lane * 4] = o;   // overwrite own q-slot
}

// ---------------------------------------------------------------- kernel D
// Deterministic two-stage BN stats over bf16 q-slots (stride 768).
__global__ __launch_bounds__(256) void bn_partial_kernel(
    const ushort* __restrict__ qkvb, float* __restrict__ ps,
    float* __restrict__ ps2) {
  const int g = blockIdx.x, c = threadIdx.x;
  float s = 0.f, s2 = 0.f;
  for (int r = 0; r < M_ / 256; ++r) {
    float v = bf2f(qkvb[((size_t)g * (M_ / 256) + r) * 768 + c]);
    s += v; s2 += v * v;
  }
  ps[g * 256 + c] = s;
  ps2[g * 256 + c] = s2;
}

__global__ __launch_bounds__(256) void bn_finalize_kernel(
    const float* __restrict__ ps, const float* __restrict__ ps2,
    const float* __restrict__ gamma, const float* __restrict__ beta,
    float* __restrict__ scale, float* __restrict__ shift) {
  const int c = threadIdx.x;
  float s = 0.f, s2 = 0.f;
  for (int g = 0; g < 256; ++g) { s += ps[g * 256 + c]; s2 += ps2[g * 256 + c]; }
  const float mean = s * (1.f / (float)M_);
  const float var = s2 * (1.f / (float)M_) - mean * mean;
  const float rstd = rsqrtf(var + 1e-5f);
  scale[c] = gamma[c] * rstd;
  shift[c] = beta[c] - mean * gamma[c] * rstd;
}

// ---------------------------------------------------------------- kernel E
// y = relu(attn*scale + shift + x), transposed back to [B][C][81] via LDS.
__global__ __launch_bounds__(256) void bn_apply_kernel(
    const ushort* __restrict__ qkvb, const float* __restrict__ x,
    const float* __restrict__ scale, const float* __restrict__ shift,
    float* __restrict__ y) {
  __shared__ float t[N_ * 65];
  const int b = blockIdx.x, tid = threadIdx.x;
  for (int c0 = 0; c0 < 256; c0 += 64) {
    __syncthreads();
    for (int e = tid; e < N_ * 64; e += 256) {
      int n = e >> 6, c = e & 63;
      t[n * 65 + c] = bf2f(qkvb[((size_t)b * N_ + n) * 768 + c0 + c]);
    }
    __syncthreads();
    for (int f = tid; f < 64 * N_; f += 256) {
      int c = f / N_, n = f - c * N_;
      float o = t[n * 65 + c];
      size_t gi = (size_t)b * (C_ * N_) + (size_t)(c0 + c) * N_ + n;
      float bn = o * scale[c0 + c] + shift[c0 + c];
      float v = bn + x[gi];
      y[gi] = v > 0.f ? v : 0.f;
    }
  }
}

// ----------------------------------------------------------------
extern "C" void kernel_launch(void* const* d_in, const int* in_sizes, int n_in,
                              void* d_out, int out_size, void* d_ws,
                              size_t ws_size, hipStream_t stream) {
  const float* x     = (const float*)d_in[0];
  const float* wq    = (const float*)d_in[1];
  const float* bq    = (const float*)d_in[2];
  const float* wk    = (const float*)d_in[3];
  const float* bk    = (const float*)d_in[4];
  const float* wv    = (const float*)d_in[5];
  const float* bv    = (const float*)d_in[6];
  const float* a     = (const float*)d_in[7];
  const float* gamma = (const float*)d_in[8];
  const float* beta  = (const float*)d_in[9];
  float* out = (float*)d_out;

  ushort* qkvb = (ushort*)d_ws;                         // M*768 bf16 (63.7MB)
  char*   lobuf = (char*)qkvb;                          // 25.2 MB alias,
                                                        // consumed pre-qkv
  ushort* tokb = qkvb + (size_t)M_ * 768;               // M*256 bf16
  ushort* wcat = tokb + (size_t)M_ * 256;               // 768*256 bf16
  float*  bcat = (float*)(wcat + 768 * 256);            // 768 f32
  int*    kidx = (int*)(bcat + 768);                    // M*9 int
  float*  ps   = (float*)(kidx + (size_t)M_ * KNN);     // 256*256
  float*  ps2  = ps + 256 * 256;                        // 256*256
  float*  scale = ps2 + 256 * 256;                      // 256
  float*  shift = scale + 256;                          // 256

  split_kernel<<<4096 + 768, 256, 0, stream>>>(
      x, tokb, lobuf, wq, bq, wk, bk, wv, bv, wcat, bcat);
  knn_kernel<<<B_, 256, 0, stream>>>(tokb, lobuf, kidx);
  qkv_mfma_kernel<<<1968, 256, 0, stream>>>(tokb, wcat, bcat, qkvb);
  attn_kernel<<<M_ / 4, 256, 0, stream>>>(qkvb, kidx, a, qkvb);
  bn_partial_kernel<<<256, 256, 0, stream>>>(qkvb, ps, ps2);
  bn_finalize_kernel<<<1, 256, 0, stream>>>(ps, ps2, gamma, beta, scale, shift);
  bn_apply_kernel<<<B_, 256, 0, stream>>>(qkvb, x, scale, shift, out);
}